// Round 13
// baseline (121.670 us; speedup 1.0000x reference)
//
#include <hip/hip_runtime.h>
#include <math.h>

#define NN 65536
#define MM 16384
#define EE 524288
#define CF 64
#define HD 128
#define OD 256
#define RPB 16        // output rows per block
#define PITCH 129     // maxbuf row pitch (de-banked)

typedef __bf16 bf16x8 __attribute__((ext_vector_type(8)));
typedef __bf16 bf16x4 __attribute__((ext_vector_type(4)));
typedef float f32x4 __attribute__((ext_vector_type(4)));

__device__ __forceinline__ unsigned enc_f(float f) {
    unsigned u = __float_as_uint(f);
    return (u & 0x80000000u) ? ~u : (u | 0x80000000u);
}
__device__ __forceinline__ float dec_f(unsigned e) {
    unsigned u = (e & 0x80000000u) ? (e ^ 0x80000000u) : ~e;
    return __uint_as_float(u);
}
#define ENC_NEG_INF 0x007FFFFFu

__device__ __forceinline__ unsigned bf_bits(float f) {
    __bf16 b = (__bf16)f;
    return (unsigned)__builtin_bit_cast(unsigned short, b);
}

// d_ws layout (>=134 MB proven usable): frag 64K | rowptr 64K | xbf 8M | pd 8M
#define WS_FRAG_OFF 0
#define WS_ROWPTR_OFF 65536
#define WS_XBF_OFF 131072
#define WS_PD_OFF (131072 + 8388608)

// Fused prologue:
// b0: weight frags (256-thread layout); b1-65: rowptr; b66-129: side outputs;
// b130-1153: x->bf16 (plain row-major); b1154+: pd.
// fragbuf[fi*256 + t] (bf16x8): fi = (w2?8:0) + nt*4 + kk; element j = W[c][n],
// c = kk*32+q*8+j, n = wv*32+nt*16+ln. Column map (K permuted, weights match):
// [x:0-63][pd:64-66][zero:67][d0 pairs:68-87][d1:88-107][d2:108-127]
__global__ void k_pre(__bf16* __restrict__ fragbuf, int* __restrict__ rowptr,
                      __bf16* __restrict__ xbf, float4* __restrict__ pdbuf,
                      const float* __restrict__ lw1, const float* __restrict__ lw2,
                      const float* __restrict__ x, const int* __restrict__ row,
                      const int* __restrict__ col,
                      const float* __restrict__ pos, const int* __restrict__ batch,
                      const int* __restrict__ idx, float* __restrict__ out) {
    const int b = blockIdx.x;
    const int t = threadIdx.x;
    if (b == 0) {
        const int lane = t & 63;
        const int wv = t >> 6;
        const int q = lane >> 4;
        const int ln = lane & 15;
        #pragma unroll
        for (int fi = 0; fi < 16; ++fi) {
            const int nt = (fi >> 2) & 1, kk = fi & 3;
            const int n = wv * 32 + nt * 16 + ln;
            bf16x8 f;
            #pragma unroll
            for (int j = 0; j < 8; ++j) {
                const int c = kk * 32 + q * 8 + j;
                const int rk = (c < 67) ? c : c - 1;
                f[j] = (fi < 8) ? (__bf16)((c == 67) ? 0.0f : lw1[rk * HD + n])
                                : (__bf16)lw2[c * HD + n];
            }
            *(bf16x8*)&fragbuf[((size_t)fi * 256 + t) * 8] = f;
        }
    } else if (b <= 65) {
        const int i = (b - 1) * 256 + t;
        if (i <= MM) {
            int lo = 0, hi = EE;
            while (lo < hi) { int mid = (lo + hi) >> 1; if (row[mid] < i) lo = mid + 1; else hi = mid; }
            rowptr[i] = lo;
        }
    } else if (b <= 129) {
        const int m = (b - 66) * 256 + t;
        if (m < MM) {
            const int s = idx[m];
            out[MM * OD + m * 3 + 0] = pos[s * 3 + 0];
            out[MM * OD + m * 3 + 1] = pos[s * 3 + 1];
            out[MM * OD + m * 3 + 2] = pos[s * 3 + 2];
            out[MM * OD + MM * 3 + m] = (float)batch[s];
        }
    } else if (b <= 1153) {
        const size_t base = ((size_t)(b - 130) * 256 + t) * 16;
        const float4* xs = (const float4*)(x + base);
        const float4 a = xs[0], c = xs[1], d = xs[2], e = xs[3];
        bf16x8 o0, o1;
        o0[0] = (__bf16)a.x; o0[1] = (__bf16)a.y; o0[2] = (__bf16)a.z; o0[3] = (__bf16)a.w;
        o0[4] = (__bf16)c.x; o0[5] = (__bf16)c.y; o0[6] = (__bf16)c.z; o0[7] = (__bf16)c.w;
        o1[0] = (__bf16)d.x; o1[1] = (__bf16)d.y; o1[2] = (__bf16)d.z; o1[3] = (__bf16)d.w;
        o1[4] = (__bf16)e.x; o1[5] = (__bf16)e.y; o1[6] = (__bf16)e.z; o1[7] = (__bf16)e.w;
        *(bf16x8*)&xbf[base] = o0;
        *(bf16x8*)&xbf[base + 8] = o1;
    } else {
        const int e = (b - 1154) * 256 + t;  // exactly EE threads
        const int r = row[e];
        const int c = col[e];
        const int s = idx[r];
        float4 pd;
        pd.x = pos[c * 3 + 0] - pos[s * 3 + 0];
        pd.y = pos[c * 3 + 1] - pos[s * 3 + 1];
        pd.z = pos[c * 3 + 2] - pos[s * 3 + 2];
        pd.w = 0.0f;
        pdbuf[e] = pd;
    }
}

// Fused edge+segmax+out, 256 threads / 4 waves (wave owns 32 n-cols).
// GEMM1 B-frags: x-half (kk=0,1) loaded DIRECTLY from xbf (global, L2-resident);
// PE-half (kk=2,3) from einP LDS. No einX buffer, no staging.
// phase1(tt): GEMM1 -> hbuf
// phase2(tt): w2f JIT; GEMM2 non-swapped; do_pe(tt+1)->einP/srow; segmax -> maxbuf
// epilogue: decode maxbuf -> final 128->256 GEMM -> out
__launch_bounds__(256)
__global__ void k_fused(const __bf16* __restrict__ xbf, const float4* __restrict__ pdbuf,
                        const int* __restrict__ row, const int* __restrict__ col,
                        const int* __restrict__ rowptr, const __bf16* __restrict__ fragbuf,
                        const float* __restrict__ lb1, const float* __restrict__ lb2,
                        const float* __restrict__ gw, const float* __restrict__ gb,
                        float* __restrict__ out) {
    __shared__ __align__(16) __bf16 einP[64][64];          // 8 KB (PE half only)
    __shared__ __align__(16) __bf16 hbuf[64][HD];          // 16 KB (reused as afin)
    __shared__ unsigned maxbuf[(RPB + 1) * PITCH];         // 8.6 KB
    __shared__ int srow[2][64];
    const int t = threadIdx.x;
    const int lane = t & 63;
    const int wv = t >> 6;          // 0..3
    const int q = lane >> 4;
    const int ln = lane & 15;
    const int lsw = ln & 7;
    const int m0 = blockIdx.x * RPB;

    const int es = rowptr[m0];
    const int ee = rowptr[m0 + RPB];
    const int ntiles = (ee - es + 63) >> 6;

    for (int i = t; i < (RPB + 1) * PITCH; i += 256) maxbuf[i] = ENC_NEG_INF;

    // PE: pd from pdbuf; one fract+sin+cos + 9 double-angle steps (threads 0-191)
    auto do_pe = [&](int tt) {
        if (t < 192) {
            const int e = t & 63, d = t >> 6;
            const int sb = tt & 1;
            const int eidx = es + tt * 64 + e;
            const int eg = min(eidx, EE - 1);
            const int esw = e & 7;
            const float4 P = pdbuf[eg];
            const float pd = (d == 0) ? P.x : ((d == 1) ? P.y : P.z);
            if (d == 0) {
                srow[sb][e] = (eidx < ee) ? (row[eg] - m0) : RPB;  // dummy row for tails
                uint2 pkt;
                pkt.x = bf_bits(P.x) | (bf_bits(P.y) << 16);
                pkt.y = bf_bits(P.z);  // col 67 = 0
                *(uint2*)&einP[e][esw * 8] = pkt;
            }
            const float fr = __builtin_amdgcn_fractf(pd * 0.5f);
            float sv = __builtin_amdgcn_sinf(fr);
            float cv = __builtin_amdgcn_cosf(fr);
            #pragma unroll
            for (int l = 0; l < 10; ++l) {
                const int jP = 4 + d * 20 + l * 2;  // column-64
                *(unsigned*)&einP[e][((jP >> 3) ^ esw) * 8 + (jP & 7)] =
                    bf_bits(sv) | (bf_bits(cv) << 16);
                const float s2 = 2.0f * sv * cv;
                const float c2 = 1.0f - 2.0f * sv * sv;
                sv = s2; cv = c2;
            }
        }
    };

    // GEMM1 weight fragments resident; GEMM2 frags JIT in phase2
    bf16x8 w1f[2][4];
    #pragma unroll
    for (int nt = 0; nt < 2; ++nt)
        #pragma unroll
        for (int kk = 0; kk < 4; ++kk)
            w1f[nt][kk] = *(const bf16x8*)&fragbuf[((size_t)(nt * 4 + kk) * 256 + t) * 8];
    float4 b1q[2];
    #pragma unroll
    for (int nt = 0; nt < 2; ++nt)
        b1q[nt] = *(const float4*)&lb1[wv * 32 + nt * 16 + q * 4];

    if (ntiles > 0) do_pe(0);
    __syncthreads();  // maxbuf init + einP/srow[0] ready

    for (int tt = 0; tt < ntiles; ++tt) {
        const int ebase = es + tt * 64;

        // ---- phase1: GEMM1 (swapped, W1 as A): D1[n][e]; n = wv*32+nt*16+q*4+rr, e = et*16+ln
        // x-half B-frags direct from global; PE-half from einP.
        int cvals[4];
        #pragma unroll
        for (int et = 0; et < 4; ++et)
            cvals[et] = col[min(ebase + et * 16 + ln, EE - 1)];

        f32x4 acc[2][4];
        #pragma unroll
        for (int nt = 0; nt < 2; ++nt)
            #pragma unroll
            for (int et = 0; et < 4; ++et)
                acc[nt][et] = (f32x4){b1q[nt].x, b1q[nt].y, b1q[nt].z, b1q[nt].w};
        #pragma unroll
        for (int et = 0; et < 4; ++et) {
            const int e = et * 16 + ln;
            const __bf16* xp = xbf + (size_t)cvals[et] * CF + q * 8;
            bf16x8 a0 = *(const bf16x8*)xp;          // k = 0..31 slice (16B)
            bf16x8 a1 = *(const bf16x8*)(xp + 32);   // k = 32..63 slice
            bf16x8 a2 = *(const bf16x8*)&einP[e][(q ^ lsw) * 8];        // k = 64..95
            bf16x8 a3 = *(const bf16x8*)&einP[e][((4 + q) ^ lsw) * 8];  // k = 96..127
            acc[0][et] = __builtin_amdgcn_mfma_f32_16x16x32_bf16(w1f[0][0], a0, acc[0][et], 0, 0, 0);
            acc[1][et] = __builtin_amdgcn_mfma_f32_16x16x32_bf16(w1f[1][0], a0, acc[1][et], 0, 0, 0);
            acc[0][et] = __builtin_amdgcn_mfma_f32_16x16x32_bf16(w1f[0][1], a1, acc[0][et], 0, 0, 0);
            acc[1][et] = __builtin_amdgcn_mfma_f32_16x16x32_bf16(w1f[1][1], a1, acc[1][et], 0, 0, 0);
            acc[0][et] = __builtin_amdgcn_mfma_f32_16x16x32_bf16(w1f[0][2], a2, acc[0][et], 0, 0, 0);
            acc[1][et] = __builtin_amdgcn_mfma_f32_16x16x32_bf16(w1f[1][2], a2, acc[1][et], 0, 0, 0);
            acc[0][et] = __builtin_amdgcn_mfma_f32_16x16x32_bf16(w1f[0][3], a3, acc[0][et], 0, 0, 0);
            acc[1][et] = __builtin_amdgcn_mfma_f32_16x16x32_bf16(w1f[1][3], a3, acc[1][et], 0, 0, 0);
        }
        // relu + b64 swizzled stores: lane holds h[e][n = wv*32+nt*16+q*4+rr]
        #pragma unroll
        for (int et = 0; et < 4; ++et) {
            const int e = et * 16 + ln;
            #pragma unroll
            for (int nt = 0; nt < 2; ++nt) {
                bf16x4 hv;
                hv[0] = (__bf16)fmaxf(acc[nt][et][0], 0.0f);
                hv[1] = (__bf16)fmaxf(acc[nt][et][1], 0.0f);
                hv[2] = (__bf16)fmaxf(acc[nt][et][2], 0.0f);
                hv[3] = (__bf16)fmaxf(acc[nt][et][3], 0.0f);
                const int chunk = wv * 4 + nt * 2 + (q >> 1);
                *(bf16x4*)&hbuf[e][((chunk ^ lsw) * 8) + (q & 1) * 4] = hv;
            }
        }
        __syncthreads();  // hbuf ready; einP phase1 reads drained

        // ---- phase2 ----
        {
            bf16x8 w2f[2][4];
            #pragma unroll
            for (int nt = 0; nt < 2; ++nt)
                #pragma unroll
                for (int kk = 0; kk < 4; ++kk)
                    w2f[nt][kk] = *(const bf16x8*)&fragbuf[((size_t)(8 + nt * 4 + kk) * 256 + t) * 8];

            // GEMM2 non-swapped (h as A, W2 as B): D2[e][n]; e = et*16+q*4+rr, n = wv*32+nt*16+ln
            f32x4 acc2[4][2];
            #pragma unroll
            for (int nt = 0; nt < 2; ++nt) {
                const float b2 = lb2[wv * 32 + nt * 16 + ln];
                #pragma unroll
                for (int et = 0; et < 4; ++et)
                    acc2[et][nt] = (f32x4){b2, b2, b2, b2};
            }
            #pragma unroll
            for (int et = 0; et < 4; ++et) {
                const int e = et * 16 + ln;
                #pragma unroll
                for (int kk = 0; kk < 4; ++kk) {
                    bf16x8 ah = *(const bf16x8*)&hbuf[e][((kk * 4 + q) ^ lsw) * 8];
                    acc2[et][0] = __builtin_amdgcn_mfma_f32_16x16x32_bf16(ah, w2f[0][kk], acc2[et][0], 0, 0, 0);
                    acc2[et][1] = __builtin_amdgcn_mfma_f32_16x16x32_bf16(ah, w2f[1][kk], acc2[et][1], 0, 0, 0);
                }
            }
            if (tt + 1 < ntiles) do_pe(tt + 1);  // einP phase1 reads drained; srow[sb^1]
            // run-compress + ds_atomicMax
            const int sb = tt & 1;
            #pragma unroll
            for (int et = 0; et < 4; ++et) {
                const int4 R = *(const int4*)&srow[sb][et * 16 + q * 4];
                #pragma unroll
                for (int nt = 0; nt < 2; ++nt) {
                    unsigned* base = maxbuf + (wv * 32 + nt * 16 + ln);
                    const f32x4 vv = acc2[et][nt];
                    int cur = R.x;
                    float m = vv[0];
                    if (R.y != cur) { atomicMax(base + cur * PITCH, enc_f(m)); cur = R.y; m = vv[1]; }
                    else m = fmaxf(m, vv[1]);
                    if (R.z != cur) { atomicMax(base + cur * PITCH, enc_f(m)); cur = R.z; m = vv[2]; }
                    else m = fmaxf(m, vv[2]);
                    if (R.w != cur) { atomicMax(base + cur * PITCH, enc_f(m)); cur = R.w; m = vv[3]; }
                    else m = fmaxf(m, vv[3]);
                    atomicMax(base + cur * PITCH, enc_f(m));
                }
            }
        }
        __syncthreads();  // einP(tt+1)/srow ready; hbuf free; (last) maxbuf complete
    }

    // ---- epilogue: decode maxbuf -> afin (overlay on hbuf), final GEMM ----
    float* afin = (float*)hbuf;  // 16*128 f32 = 8 KB
    for (int i = t; i < RPB * HD; i += 256) {
        const unsigned e = maxbuf[(i >> 7) * PITCH + (i & 127)];
        afin[i] = (e == ENC_NEG_INF) ? 0.0f : dec_f(e);
    }
    __syncthreads();

    const int j4 = (t & 63) * 4;
    const int rbase = (t >> 6) * 4;
    float facc[4][4];
    const float4 bias = *(const float4*)&gb[j4];
    #pragma unroll
    for (int r = 0; r < 4; ++r) { facc[r][0] = bias.x; facc[r][1] = bias.y; facc[r][2] = bias.z; facc[r][3] = bias.w; }
    for (int k = 0; k < 128; k += 4) {
        float4 w0 = *(const float4*)&gw[(k + 0) * OD + j4];
        float4 w1 = *(const float4*)&gw[(k + 1) * OD + j4];
        float4 w2 = *(const float4*)&gw[(k + 2) * OD + j4];
        float4 w3 = *(const float4*)&gw[(k + 3) * OD + j4];
        #pragma unroll
        for (int r = 0; r < 4; ++r) {
            float4 av = *(const float4*)&afin[(rbase + r) * HD + k];
            facc[r][0] += av.x * w0.x + av.y * w1.x + av.z * w2.x + av.w * w3.x;
            facc[r][1] += av.x * w0.y + av.y * w1.y + av.z * w2.y + av.w * w3.y;
            facc[r][2] += av.x * w0.z + av.y * w1.z + av.z * w2.z + av.w * w3.z;
            facc[r][3] += av.x * w0.w + av.y * w1.w + av.z * w2.w + av.w * w3.w;
        }
    }
    #pragma unroll
    for (int r = 0; r < 4; ++r) {
        float4 v; v.x = facc[r][0]; v.y = facc[r][1]; v.z = facc[r][2]; v.w = facc[r][3];
        *(float4*)&out[(size_t)(m0 + rbase + r) * OD + j4] = v;
    }
}

extern "C" void kernel_launch(void* const* d_in, const int* in_sizes, int n_in,
                              void* d_out, int out_size, void* d_ws, size_t ws_size,
                              hipStream_t stream) {
    const float* x   = (const float*)d_in[0];
    const float* pos = (const float*)d_in[1];
    const int* batch = (const int*)d_in[2];
    const int* idx   = (const int*)d_in[3];
    const int* row   = (const int*)d_in[4];
    const int* col   = (const int*)d_in[5];
    const float* lw1 = (const float*)d_in[6];
    const float* lb1 = (const float*)d_in[7];
    const float* lw2 = (const float*)d_in[8];
    const float* lb2 = (const float*)d_in[9];
    const float* gw  = (const float*)d_in[10];
    const float* gb  = (const float*)d_in[11];
    float* out = (float*)d_out;
    __bf16* fragbuf = (__bf16*)((char*)d_ws + WS_FRAG_OFF);
    int* rowptr     = (int*)((char*)d_ws + WS_ROWPTR_OFF);
    __bf16* xbf     = (__bf16*)((char*)d_ws + WS_XBF_OFF);
    float4* pdbuf   = (float4*)((char*)d_ws + WS_PD_OFF);

    hipLaunchKernelGGL(k_pre, dim3(1 + 65 + 64 + 1024 + 2048), dim3(256), 0, stream,
                       fragbuf, rowptr, xbf, pdbuf, lw1, lw2, x, row, col, pos, batch, idx, out);
    hipLaunchKernelGGL(k_fused, dim3(MM / RPB), dim3(256), 0, stream,
                       xbf, pdbuf, row, col, rowptr, fragbuf, lb1, lb2, gw, gb, out);
}

// Round 14
// 118.793 us; speedup vs baseline: 1.0242x; 1.0242x over previous
//
#include <hip/hip_runtime.h>
#include <math.h>

#define NN 65536
#define MM 16384
#define EE 524288
#define CF 64
#define HD 128
#define OD 256
#define RPB 8         // output rows per block (2048 blocks, small maxbuf -> 4 blocks/CU)
#define PITCH 129     // maxbuf row pitch (de-banked)

typedef __bf16 bf16x8 __attribute__((ext_vector_type(8)));
typedef __bf16 bf16x4 __attribute__((ext_vector_type(4)));
typedef float f32x4 __attribute__((ext_vector_type(4)));

__device__ __forceinline__ unsigned enc_f(float f) {
    unsigned u = __float_as_uint(f);
    return (u & 0x80000000u) ? ~u : (u | 0x80000000u);
}
__device__ __forceinline__ float dec_f(unsigned e) {
    unsigned u = (e & 0x80000000u) ? (e ^ 0x80000000u) : ~e;
    return __uint_as_float(u);
}
#define ENC_NEG_INF 0x007FFFFFu

__device__ __forceinline__ unsigned bf_bits(float f) {
    __bf16 b = (__bf16)f;
    return (unsigned)__builtin_bit_cast(unsigned short, b);
}

// d_ws layout (>=134 MB proven usable): frag 64K | rowptr 64K | xbf 8M | pd 8M
#define WS_FRAG_OFF 0
#define WS_ROWPTR_OFF 65536
#define WS_XBF_OFF 131072
#define WS_PD_OFF (131072 + 8388608)

// Fused prologue:
// b0: weight frags; b1-65: rowptr; b66-129: side outputs; b130-1153: x->bf16; b1154+: pd.
// fragbuf[fi*256 + t] (bf16x8): fi = (w2?8:0) + nt*4 + kk; element j = W[c][n],
// c = kk*32+q*8+j, n = wv*32+nt*16+ln. Column map (K permuted, weights match):
// [x:0-63][pd:64-66][zero:67][d0 pairs:68-87][d1:88-107][d2:108-127]
__global__ void k_pre(__bf16* __restrict__ fragbuf, int* __restrict__ rowptr,
                      __bf16* __restrict__ xbf, float4* __restrict__ pdbuf,
                      const float* __restrict__ lw1, const float* __restrict__ lw2,
                      const float* __restrict__ x, const int* __restrict__ row,
                      const int* __restrict__ col,
                      const float* __restrict__ pos, const int* __restrict__ batch,
                      const int* __restrict__ idx, float* __restrict__ out) {
    const int b = blockIdx.x;
    const int t = threadIdx.x;
    if (b == 0) {
        const int lane = t & 63;
        const int wv = t >> 6;
        const int q = lane >> 4;
        const int ln = lane & 15;
        #pragma unroll
        for (int fi = 0; fi < 16; ++fi) {
            const int nt = (fi >> 2) & 1, kk = fi & 3;
            const int n = wv * 32 + nt * 16 + ln;
            bf16x8 f;
            #pragma unroll
            for (int j = 0; j < 8; ++j) {
                const int c = kk * 32 + q * 8 + j;
                const int rk = (c < 67) ? c : c - 1;
                f[j] = (fi < 8) ? (__bf16)((c == 67) ? 0.0f : lw1[rk * HD + n])
                                : (__bf16)lw2[c * HD + n];
            }
            *(bf16x8*)&fragbuf[((size_t)fi * 256 + t) * 8] = f;
        }
    } else if (b <= 65) {
        const int i = (b - 1) * 256 + t;
        if (i <= MM) {
            int lo = 0, hi = EE;
            while (lo < hi) { int mid = (lo + hi) >> 1; if (row[mid] < i) lo = mid + 1; else hi = mid; }
            rowptr[i] = lo;
        }
    } else if (b <= 129) {
        const int m = (b - 66) * 256 + t;
        if (m < MM) {
            const int s = idx[m];
            out[MM * OD + m * 3 + 0] = pos[s * 3 + 0];
            out[MM * OD + m * 3 + 1] = pos[s * 3 + 1];
            out[MM * OD + m * 3 + 2] = pos[s * 3 + 2];
            out[MM * OD + MM * 3 + m] = (float)batch[s];
        }
    } else if (b <= 1153) {
        const size_t base = ((size_t)(b - 130) * 256 + t) * 16;
        const float4* xs = (const float4*)(x + base);
        const float4 a = xs[0], c = xs[1], d = xs[2], e = xs[3];
        bf16x8 o0, o1;
        o0[0] = (__bf16)a.x; o0[1] = (__bf16)a.y; o0[2] = (__bf16)a.z; o0[3] = (__bf16)a.w;
        o0[4] = (__bf16)c.x; o0[5] = (__bf16)c.y; o0[6] = (__bf16)c.z; o0[7] = (__bf16)c.w;
        o1[0] = (__bf16)d.x; o1[1] = (__bf16)d.y; o1[2] = (__bf16)d.z; o1[3] = (__bf16)d.w;
        o1[4] = (__bf16)e.x; o1[5] = (__bf16)e.y; o1[6] = (__bf16)e.z; o1[7] = (__bf16)e.w;
        *(bf16x8*)&xbf[base] = o0;
        *(bf16x8*)&xbf[base + 8] = o1;
    } else {
        const int e = (b - 1154) * 256 + t;  // exactly EE threads
        const int r = row[e];
        const int c = col[e];
        const int s = idx[r];
        float4 pd;
        pd.x = pos[c * 3 + 0] - pos[s * 3 + 0];
        pd.y = pos[c * 3 + 1] - pos[s * 3 + 1];
        pd.z = pos[c * 3 + 2] - pos[s * 3 + 2];
        pd.w = 0.0f;
        pdbuf[e] = pd;
    }
}

// Fully fused edge+segmax+out (R11 structure, RPB=8). Block owns rows [m0, m0+8).
// phase1(tt): GEMM1(einX, einP) -> hbuf
// phase2(tt): commit(tt+1)->einX + issue(tt+2); w2f JIT; GEMM2 non-swapped;
//             do_pe(tt+1)->einP/srow; run-compress segmax -> ds_atomicMax maxbuf
// epilogue: decode maxbuf -> final 128->256 GEMM -> out
__launch_bounds__(256)
__global__ void k_fused(const __bf16* __restrict__ xbf, const float4* __restrict__ pdbuf,
                        const int* __restrict__ row, const int* __restrict__ col,
                        const int* __restrict__ rowptr, const __bf16* __restrict__ fragbuf,
                        const float* __restrict__ lb1, const float* __restrict__ lb2,
                        const float* __restrict__ gw, const float* __restrict__ gb,
                        float* __restrict__ out) {
    __shared__ __align__(16) __bf16 einX[64][64];          // 8 KB
    __shared__ __align__(16) __bf16 einP[64][64];          // 8 KB
    __shared__ __align__(16) __bf16 hbuf[64][HD];          // 16 KB (reused as afin)
    __shared__ unsigned maxbuf[(RPB + 1) * PITCH];         // 4.6 KB
    __shared__ int srow[2][64];
    const int t = threadIdx.x;
    const int lane = t & 63;
    const int wv = t >> 6;          // 0..3
    const int q = lane >> 4;
    const int ln = lane & 15;
    const int lsw = ln & 7;
    const int m0 = blockIdx.x * RPB;

    const int es = rowptr[m0];
    const int ee = rowptr[m0 + RPB];
    const int ntiles = (ee - es + 63) >> 6;

    for (int i = t; i < (RPB + 1) * PITCH; i += 256) maxbuf[i] = ENC_NEG_INF;

    // register staging from xbf: thread stages edge pe_e, 16-col slice pe_part
    const int pe_e = t >> 2, pe_part = t & 3, pe_esw = pe_e & 7;
    bf16x8 s0, s1;
    auto issue = [&](int tt) {
        const int eg = min(es + tt * 64 + pe_e, EE - 1);
        const int c = col[eg];
        const bf16x8* xr = (const bf16x8*)(xbf + (size_t)c * CF) + pe_part * 2;
        s0 = xr[0]; s1 = xr[1];
    };
    auto commit = [&]() {
        *(bf16x8*)&einX[pe_e][((pe_part * 2 + 0) ^ pe_esw) * 8] = s0;
        *(bf16x8*)&einX[pe_e][((pe_part * 2 + 1) ^ pe_esw) * 8] = s1;
    };
    // PE: pd from pdbuf; one fract+sin+cos + 9 double-angle steps (threads 0-191)
    auto do_pe = [&](int tt) {
        if (t < 192) {
            const int e = t & 63, d = t >> 6;
            const int sb = tt & 1;
            const int eidx = es + tt * 64 + e;
            const int eg = min(eidx, EE - 1);
            const int esw = e & 7;
            const float4 P = pdbuf[eg];
            const float pd = (d == 0) ? P.x : ((d == 1) ? P.y : P.z);
            if (d == 0) {
                srow[sb][e] = (eidx < ee) ? (row[eg] - m0) : RPB;  // dummy row for tails
                uint2 pkt;
                pkt.x = bf_bits(P.x) | (bf_bits(P.y) << 16);
                pkt.y = bf_bits(P.z);  // col 67 = 0
                *(uint2*)&einP[e][esw * 8] = pkt;
            }
            const float fr = __builtin_amdgcn_fractf(pd * 0.5f);
            float sv = __builtin_amdgcn_sinf(fr);
            float cv = __builtin_amdgcn_cosf(fr);
            #pragma unroll
            for (int l = 0; l < 10; ++l) {
                const int jP = 4 + d * 20 + l * 2;  // column-64
                *(unsigned*)&einP[e][((jP >> 3) ^ esw) * 8 + (jP & 7)] =
                    bf_bits(sv) | (bf_bits(cv) << 16);
                const float s2 = 2.0f * sv * cv;
                const float c2 = 1.0f - 2.0f * sv * sv;
                sv = s2; cv = c2;
            }
        }
    };

    // GEMM1 weight fragments resident; GEMM2 frags JIT in phase2
    bf16x8 w1f[2][4];
    #pragma unroll
    for (int nt = 0; nt < 2; ++nt)
        #pragma unroll
        for (int kk = 0; kk < 4; ++kk)
            w1f[nt][kk] = *(const bf16x8*)&fragbuf[((size_t)(nt * 4 + kk) * 256 + t) * 8];
    float4 b1q[2];
    #pragma unroll
    for (int nt = 0; nt < 2; ++nt)
        b1q[nt] = *(const float4*)&lb1[wv * 32 + nt * 16 + q * 4];

    if (ntiles > 0) {
        issue(0);
        commit();
        do_pe(0);
        if (ntiles > 1) issue(1);  // consumed by commit in phase2(0)
    }
    __syncthreads();  // maxbuf init + einX/einP/srow[0] ready

    for (int tt = 0; tt < ntiles; ++tt) {
        // ---- phase1: GEMM1 (swapped, W1 as A): D1[n][e] ----
        f32x4 acc[2][4];
        #pragma unroll
        for (int nt = 0; nt < 2; ++nt)
            #pragma unroll
            for (int et = 0; et < 4; ++et)
                acc[nt][et] = (f32x4){b1q[nt].x, b1q[nt].y, b1q[nt].z, b1q[nt].w};
        #pragma unroll
        for (int et = 0; et < 4; ++et) {
            const int e = et * 16 + ln;
            bf16x8 a[4];
            a[0] = *(const bf16x8*)&einX[e][(q ^ lsw) * 8];
            a[1] = *(const bf16x8*)&einX[e][((4 + q) ^ lsw) * 8];
            a[2] = *(const bf16x8*)&einP[e][(q ^ lsw) * 8];
            a[3] = *(const bf16x8*)&einP[e][((4 + q) ^ lsw) * 8];
            #pragma unroll
            for (int kk = 0; kk < 4; ++kk) {
                acc[0][et] = __builtin_amdgcn_mfma_f32_16x16x32_bf16(w1f[0][kk], a[kk], acc[0][et], 0, 0, 0);
                acc[1][et] = __builtin_amdgcn_mfma_f32_16x16x32_bf16(w1f[1][kk], a[kk], acc[1][et], 0, 0, 0);
            }
        }
        // relu + b64 swizzled stores: lane holds h[e][n = wv*32+nt*16+q*4+r]
        #pragma unroll
        for (int et = 0; et < 4; ++et) {
            const int e = et * 16 + ln;
            #pragma unroll
            for (int nt = 0; nt < 2; ++nt) {
                bf16x4 hv;
                hv[0] = (__bf16)fmaxf(acc[nt][et][0], 0.0f);
                hv[1] = (__bf16)fmaxf(acc[nt][et][1], 0.0f);
                hv[2] = (__bf16)fmaxf(acc[nt][et][2], 0.0f);
                hv[3] = (__bf16)fmaxf(acc[nt][et][3], 0.0f);
                const int chunk = wv * 4 + nt * 2 + (q >> 1);
                *(bf16x4*)&hbuf[e][((chunk ^ lsw) * 8) + (q & 1) * 4] = hv;
            }
        }
        __syncthreads();  // hbuf ready; einX/einP phase1 reads drained

        // ---- phase2 ----
        {
            if (tt + 1 < ntiles) { commit(); issue(tt + 2 < ntiles ? tt + 2 : tt + 1); }
            bf16x8 w2f[2][4];
            #pragma unroll
            for (int nt = 0; nt < 2; ++nt)
                #pragma unroll
                for (int kk = 0; kk < 4; ++kk)
                    w2f[nt][kk] = *(const bf16x8*)&fragbuf[((size_t)(8 + nt * 4 + kk) * 256 + t) * 8];

            // GEMM2 non-swapped (h as A, W2 as B): D2[e][n]
            f32x4 acc2[4][2];
            #pragma unroll
            for (int nt = 0; nt < 2; ++nt) {
                const float b2 = lb2[wv * 32 + nt * 16 + ln];
                #pragma unroll
                for (int et = 0; et < 4; ++et)
                    acc2[et][nt] = (f32x4){b2, b2, b2, b2};
            }
            #pragma unroll
            for (int et = 0; et < 4; ++et) {
                const int e = et * 16 + ln;
                #pragma unroll
                for (int kk = 0; kk < 4; ++kk) {
                    bf16x8 ah = *(const bf16x8*)&hbuf[e][((kk * 4 + q) ^ lsw) * 8];
                    acc2[et][0] = __builtin_amdgcn_mfma_f32_16x16x32_bf16(ah, w2f[0][kk], acc2[et][0], 0, 0, 0);
                    acc2[et][1] = __builtin_amdgcn_mfma_f32_16x16x32_bf16(ah, w2f[1][kk], acc2[et][1], 0, 0, 0);
                }
            }
            if (tt + 1 < ntiles) do_pe(tt + 1);  // einP phase1 reads drained; srow[sb^1]
            // run-compress + ds_atomicMax; lane: e = et*16+q*4+rr, n = wv*32+nt*16+ln
            const int sb = tt & 1;
            #pragma unroll
            for (int et = 0; et < 4; ++et) {
                const int4 R = *(const int4*)&srow[sb][et * 16 + q * 4];
                #pragma unroll
                for (int nt = 0; nt < 2; ++nt) {
                    unsigned* base = maxbuf + (wv * 32 + nt * 16 + ln);
                    const f32x4 vv = acc2[et][nt];
                    int cur = R.x;
                    float m = vv[0];
                    if (R.y != cur) { atomicMax(base + cur * PITCH, enc_f(m)); cur = R.y; m = vv[1]; }
                    else m = fmaxf(m, vv[1]);
                    if (R.z != cur) { atomicMax(base + cur * PITCH, enc_f(m)); cur = R.z; m = vv[2]; }
                    else m = fmaxf(m, vv[2]);
                    if (R.w != cur) { atomicMax(base + cur * PITCH, enc_f(m)); cur = R.w; m = vv[3]; }
                    else m = fmaxf(m, vv[3]);
                    atomicMax(base + cur * PITCH, enc_f(m));
                }
            }
        }
        __syncthreads();  // einX/einP(tt+1)/srow ready; hbuf free; (last) maxbuf complete
    }

    // ---- epilogue: decode maxbuf -> afin (overlay on hbuf), final GEMM ----
    float* afin = (float*)hbuf;  // 8*128 f32 = 4 KB
    for (int i = t; i < RPB * HD; i += 256) {
        const unsigned e = maxbuf[(i >> 7) * PITCH + (i & 127)];
        afin[i] = (e == ENC_NEG_INF) ? 0.0f : dec_f(e);
    }
    __syncthreads();

    const int j4 = (t & 63) * 4;
    const int rbase = (t >> 6) * 2;  // 4 groups x 2 rows = 8 rows
    float facc[2][4];
    const float4 bias = *(const float4*)&gb[j4];
    #pragma unroll
    for (int r = 0; r < 2; ++r) { facc[r][0] = bias.x; facc[r][1] = bias.y; facc[r][2] = bias.z; facc[r][3] = bias.w; }
    for (int k = 0; k < 128; k += 4) {
        float4 w0 = *(const float4*)&gw[(k + 0) * OD + j4];
        float4 w1 = *(const float4*)&gw[(k + 1) * OD + j4];
        float4 w2 = *(const float4*)&gw[(k + 2) * OD + j4];
        float4 w3 = *(const float4*)&gw[(k + 3) * OD + j4];
        #pragma unroll
        for (int r = 0; r < 2; ++r) {
            float4 av = *(const float4*)&afin[(rbase + r) * HD + k];
            facc[r][0] += av.x * w0.x + av.y * w1.x + av.z * w2.x + av.w * w3.x;
            facc[r][1] += av.x * w0.y + av.y * w1.y + av.z * w2.y + av.w * w3.y;
            facc[r][2] += av.x * w0.z + av.y * w1.z + av.z * w2.z + av.w * w3.z;
            facc[r][3] += av.x * w0.w + av.y * w1.w + av.z * w2.w + av.w * w3.w;
        }
    }
    #pragma unroll
    for (int r = 0; r < 2; ++r) {
        float4 v; v.x = facc[r][0]; v.y = facc[r][1]; v.z = facc[r][2]; v.w = facc[r][3];
        *(float4*)&out[(size_t)(m0 + rbase + r) * OD + j4] = v;
    }
}

extern "C" void kernel_launch(void* const* d_in, const int* in_sizes, int n_in,
                              void* d_out, int out_size, void* d_ws, size_t ws_size,
                              hipStream_t stream) {
    const float* x   = (const float*)d_in[0];
    const float* pos = (const float*)d_in[1];
    const int* batch = (const int*)d_in[2];
    const int* idx   = (const int*)d_in[3];
    const int* row   = (const int*)d_in[4];
    const int* col   = (const int*)d_in[5];
    const float* lw1 = (const float*)d_in[6];
    const float* lb1 = (const float*)d_in[7];
    const float* lw2 = (const float*)d_in[8];
    const float* lb2 = (const float*)d_in[9];
    const float* gw  = (const float*)d_in[10];
    const float* gb  = (const float*)d_in[11];
    float* out = (float*)d_out;
    __bf16* fragbuf = (__bf16*)((char*)d_ws + WS_FRAG_OFF);
    int* rowptr     = (int*)((char*)d_ws + WS_ROWPTR_OFF);
    __bf16* xbf     = (__bf16*)((char*)d_ws + WS_XBF_OFF);
    float4* pdbuf   = (float4*)((char*)d_ws + WS_PD_OFF);

    hipLaunchKernelGGL(k_pre, dim3(1 + 65 + 64 + 1024 + 2048), dim3(256), 0, stream,
                       fragbuf, rowptr, xbf, pdbuf, lw1, lw2, x, row, col, pos, batch, idx, out);
    hipLaunchKernelGGL(k_fused, dim3(MM / RPB), dim3(256), 0, stream,
                       xbf, pdbuf, row, col, rowptr, fragbuf, lb1, lb2, gw, gb, out);
}

// Round 15
// 101.656 us; speedup vs baseline: 1.1969x; 1.1686x over previous
//
#include <hip/hip_runtime.h>
#include <math.h>

#define NN 65536
#define MM 16384
#define EE 524288
#define CF 64
#define HD 128
#define OD 256
#define RPB 16        // output rows per block
#define ET 128        // edges per tile (two 64-edge halves between one barrier pair)
#define PITCH 129     // maxbuf row pitch (de-banked)

typedef __bf16 bf16x8 __attribute__((ext_vector_type(8)));
typedef __bf16 bf16x4 __attribute__((ext_vector_type(4)));
typedef float f32x4 __attribute__((ext_vector_type(4)));

__device__ __forceinline__ unsigned enc_f(float f) {
    unsigned u = __float_as_uint(f);
    return (u & 0x80000000u) ? ~u : (u | 0x80000000u);
}
__device__ __forceinline__ float dec_f(unsigned e) {
    unsigned u = (e & 0x80000000u) ? (e ^ 0x80000000u) : ~e;
    return __uint_as_float(u);
}
#define ENC_NEG_INF 0x007FFFFFu

__device__ __forceinline__ unsigned bf_bits(float f) {
    __bf16 b = (__bf16)f;
    return (unsigned)__builtin_bit_cast(unsigned short, b);
}

// d_ws layout (>=134 MB proven usable): frag 64K | rowptr 64K | xbf 8M | pd 8M
#define WS_FRAG_OFF 0
#define WS_ROWPTR_OFF 65536
#define WS_XBF_OFF 131072
#define WS_PD_OFF (131072 + 8388608)

// Fused prologue (identical to R11):
// b0: weight frags; b1-65: rowptr; b66-129: side outputs; b130-1153: x->bf16; b1154+: pd.
// fragbuf[fi*256 + t] (bf16x8): fi = (w2?8:0) + nt*4 + kk; element j = W[c][n],
// c = kk*32+q*8+j, n = wv*32+nt*16+ln. Column map (K permuted, weights match):
// [x:0-63][pd:64-66][zero:67][d0 pairs:68-87][d1:88-107][d2:108-127]
__global__ void k_pre(__bf16* __restrict__ fragbuf, int* __restrict__ rowptr,
                      __bf16* __restrict__ xbf, float4* __restrict__ pdbuf,
                      const float* __restrict__ lw1, const float* __restrict__ lw2,
                      const float* __restrict__ x, const int* __restrict__ row,
                      const int* __restrict__ col,
                      const float* __restrict__ pos, const int* __restrict__ batch,
                      const int* __restrict__ idx, float* __restrict__ out) {
    const int b = blockIdx.x;
    const int t = threadIdx.x;
    if (b == 0) {
        const int lane = t & 63;
        const int wv = t >> 6;
        const int q = lane >> 4;
        const int ln = lane & 15;
        #pragma unroll
        for (int fi = 0; fi < 16; ++fi) {
            const int nt = (fi >> 2) & 1, kk = fi & 3;
            const int n = wv * 32 + nt * 16 + ln;
            bf16x8 f;
            #pragma unroll
            for (int j = 0; j < 8; ++j) {
                const int c = kk * 32 + q * 8 + j;
                const int rk = (c < 67) ? c : c - 1;
                f[j] = (fi < 8) ? (__bf16)((c == 67) ? 0.0f : lw1[rk * HD + n])
                                : (__bf16)lw2[c * HD + n];
            }
            *(bf16x8*)&fragbuf[((size_t)fi * 256 + t) * 8] = f;
        }
    } else if (b <= 65) {
        const int i = (b - 1) * 256 + t;
        if (i <= MM) {
            int lo = 0, hi = EE;
            while (lo < hi) { int mid = (lo + hi) >> 1; if (row[mid] < i) lo = mid + 1; else hi = mid; }
            rowptr[i] = lo;
        }
    } else if (b <= 129) {
        const int m = (b - 66) * 256 + t;
        if (m < MM) {
            const int s = idx[m];
            out[MM * OD + m * 3 + 0] = pos[s * 3 + 0];
            out[MM * OD + m * 3 + 1] = pos[s * 3 + 1];
            out[MM * OD + m * 3 + 2] = pos[s * 3 + 2];
            out[MM * OD + MM * 3 + m] = (float)batch[s];
        }
    } else if (b <= 1153) {
        const size_t base = ((size_t)(b - 130) * 256 + t) * 16;
        const float4* xs = (const float4*)(x + base);
        const float4 a = xs[0], c = xs[1], d = xs[2], e = xs[3];
        bf16x8 o0, o1;
        o0[0] = (__bf16)a.x; o0[1] = (__bf16)a.y; o0[2] = (__bf16)a.z; o0[3] = (__bf16)a.w;
        o0[4] = (__bf16)c.x; o0[5] = (__bf16)c.y; o0[6] = (__bf16)c.z; o0[7] = (__bf16)c.w;
        o1[0] = (__bf16)d.x; o1[1] = (__bf16)d.y; o1[2] = (__bf16)d.z; o1[3] = (__bf16)d.w;
        o1[4] = (__bf16)e.x; o1[5] = (__bf16)e.y; o1[6] = (__bf16)e.z; o1[7] = (__bf16)e.w;
        *(bf16x8*)&xbf[base] = o0;
        *(bf16x8*)&xbf[base + 8] = o1;
    } else {
        const int e = (b - 1154) * 256 + t;  // exactly EE threads
        const int r = row[e];
        const int c = col[e];
        const int s = idx[r];
        float4 pd;
        pd.x = pos[c * 3 + 0] - pos[s * 3 + 0];
        pd.y = pos[c * 3 + 1] - pos[s * 3 + 1];
        pd.z = pos[c * 3 + 2] - pos[s * 3 + 2];
        pd.w = 0.0f;
        pdbuf[e] = pd;
    }
}

// Fully fused edge+segmax+out, 128-edge tiles (two 64-edge halves per barrier pair).
// phase1(tt): GEMM1 half0+half1 -> hbuf; issue(tt+1) between halves
// phase2(tt): commit(tt+1)->einX; w2f JIT; per half {GEMM2; segmax}; do_pe(tt+1)
// epilogue: decode maxbuf -> final 128->256 GEMM -> out
__launch_bounds__(256)
__global__ void k_fused(const __bf16* __restrict__ xbf, const float4* __restrict__ pdbuf,
                        const int* __restrict__ row, const int* __restrict__ col,
                        const int* __restrict__ rowptr, const __bf16* __restrict__ fragbuf,
                        const float* __restrict__ lb1, const float* __restrict__ lb2,
                        const float* __restrict__ gw, const float* __restrict__ gb,
                        float* __restrict__ out) {
    __shared__ __align__(16) __bf16 einX[ET][64];          // 16 KB
    __shared__ __align__(16) __bf16 einP[ET][64];          // 16 KB
    __shared__ __align__(16) __bf16 hbuf[ET][HD];          // 32 KB (reused as afin)
    __shared__ unsigned maxbuf[(RPB + 1) * PITCH];         // 8.8 KB
    __shared__ int srow[2][ET];
    const int t = threadIdx.x;
    const int lane = t & 63;
    const int wv = t >> 6;          // 0..3
    const int q = lane >> 4;
    const int ln = lane & 15;
    const int lsw = ln & 7;
    const int m0 = blockIdx.x * RPB;

    const int es = rowptr[m0];
    const int ee = rowptr[m0 + RPB];
    const int ntiles = (ee - es + ET - 1) >> 7;

    for (int i = t; i < (RPB + 1) * PITCH; i += 256) maxbuf[i] = ENC_NEG_INF;

    // register staging from xbf: thread stages edge pe_e = t>>1, 32-col half pe_part = t&1
    const int pe_e = t >> 1, pe_part = t & 1, pe_esw = pe_e & 7;
    bf16x8 s0, s1, s2, s3;
    auto issue = [&](int tt) {
        const int eg = min(es + tt * ET + pe_e, EE - 1);
        const int c = col[eg];
        const bf16x8* xr = (const bf16x8*)(xbf + (size_t)c * CF + pe_part * 32);
        s0 = xr[0]; s1 = xr[1]; s2 = xr[2]; s3 = xr[3];
    };
    auto commit = [&]() {
        *(bf16x8*)&einX[pe_e][((pe_part * 4 + 0) ^ pe_esw) * 8] = s0;
        *(bf16x8*)&einX[pe_e][((pe_part * 4 + 1) ^ pe_esw) * 8] = s1;
        *(bf16x8*)&einX[pe_e][((pe_part * 4 + 2) ^ pe_esw) * 8] = s2;
        *(bf16x8*)&einX[pe_e][((pe_part * 4 + 3) ^ pe_esw) * 8] = s3;
    };
    // PE over 384 (e,d) pairs: i=0 -> d=0,1 (e=t&127); i=1 -> d=2 (t<128)
    auto do_pe = [&](int tt) {
        const int sb = tt & 1;
        #pragma unroll
        for (int i = 0; i < 2; ++i) {
            const int p = i * 256 + t;
            if (p < 384) {
                const int e = p & 127, d = p >> 7;
                const int eidx = es + tt * ET + e;
                const int eg = min(eidx, EE - 1);
                const int esw = e & 7;
                const float4 P = pdbuf[eg];
                const float pd = (d == 0) ? P.x : ((d == 1) ? P.y : P.z);
                if (d == 0) {
                    srow[sb][e] = (eidx < ee) ? (row[eg] - m0) : RPB;  // dummy row for tails
                    uint2 pkt;
                    pkt.x = bf_bits(P.x) | (bf_bits(P.y) << 16);
                    pkt.y = bf_bits(P.z);  // col 67 = 0
                    *(uint2*)&einP[e][esw * 8] = pkt;
                }
                const float fr = __builtin_amdgcn_fractf(pd * 0.5f);
                float sv = __builtin_amdgcn_sinf(fr);
                float cv = __builtin_amdgcn_cosf(fr);
                #pragma unroll
                for (int l = 0; l < 10; ++l) {
                    const int jP = 4 + d * 20 + l * 2;  // column-64
                    *(unsigned*)&einP[e][((jP >> 3) ^ esw) * 8 + (jP & 7)] =
                        bf_bits(sv) | (bf_bits(cv) << 16);
                    const float s2 = 2.0f * sv * cv;
                    const float c2 = 1.0f - 2.0f * sv * sv;
                    sv = s2; cv = c2;
                }
            }
        }
    };

    // GEMM1 weight fragments resident; GEMM2 frags JIT in phase2
    bf16x8 w1f[2][4];
    #pragma unroll
    for (int nt = 0; nt < 2; ++nt)
        #pragma unroll
        for (int kk = 0; kk < 4; ++kk)
            w1f[nt][kk] = *(const bf16x8*)&fragbuf[((size_t)(nt * 4 + kk) * 256 + t) * 8];
    float4 b1q[2];
    #pragma unroll
    for (int nt = 0; nt < 2; ++nt)
        b1q[nt] = *(const float4*)&lb1[wv * 32 + nt * 16 + q * 4];

    if (ntiles > 0) {
        issue(0);
        commit();
        do_pe(0);
        if (ntiles > 1) issue(1);  // consumed by commit in phase2(0)
    }
    __syncthreads();  // maxbuf init + einX/einP/srow[0] ready

    for (int tt = 0; tt < ntiles; ++tt) {
        // ---- phase1: GEMM1 (swapped, W1 as A): D1[n][e], two 64-edge halves ----
        #pragma unroll
        for (int hh = 0; hh < 2; ++hh) {
            f32x4 acc[2][4];
            #pragma unroll
            for (int nt = 0; nt < 2; ++nt)
                #pragma unroll
                for (int et = 0; et < 4; ++et)
                    acc[nt][et] = (f32x4){b1q[nt].x, b1q[nt].y, b1q[nt].z, b1q[nt].w};
            #pragma unroll
            for (int et = 0; et < 4; ++et) {
                const int e = hh * 64 + et * 16 + ln;
                bf16x8 a[4];
                a[0] = *(const bf16x8*)&einX[e][(q ^ lsw) * 8];
                a[1] = *(const bf16x8*)&einX[e][((4 + q) ^ lsw) * 8];
                a[2] = *(const bf16x8*)&einP[e][(q ^ lsw) * 8];
                a[3] = *(const bf16x8*)&einP[e][((4 + q) ^ lsw) * 8];
                #pragma unroll
                for (int kk = 0; kk < 4; ++kk) {
                    acc[0][et] = __builtin_amdgcn_mfma_f32_16x16x32_bf16(w1f[0][kk], a[kk], acc[0][et], 0, 0, 0);
                    acc[1][et] = __builtin_amdgcn_mfma_f32_16x16x32_bf16(w1f[1][kk], a[kk], acc[1][et], 0, 0, 0);
                }
            }
            if (hh == 0 && tt + 1 < ntiles) issue(tt + 1);  // hide gather under half1
            // relu + b64 swizzled stores: lane holds h[e][n = wv*32+nt*16+q*4+r]
            #pragma unroll
            for (int et = 0; et < 4; ++et) {
                const int e = hh * 64 + et * 16 + ln;
                #pragma unroll
                for (int nt = 0; nt < 2; ++nt) {
                    bf16x4 hv;
                    hv[0] = (__bf16)fmaxf(acc[nt][et][0], 0.0f);
                    hv[1] = (__bf16)fmaxf(acc[nt][et][1], 0.0f);
                    hv[2] = (__bf16)fmaxf(acc[nt][et][2], 0.0f);
                    hv[3] = (__bf16)fmaxf(acc[nt][et][3], 0.0f);
                    const int chunk = wv * 4 + nt * 2 + (q >> 1);
                    *(bf16x4*)&hbuf[e][((chunk ^ lsw) * 8) + (q & 1) * 4] = hv;
                }
            }
        }
        __syncthreads();  // hbuf ready; einX/einP phase1 reads drained

        // ---- phase2 ----
        {
            if (tt + 1 < ntiles) commit();
            bf16x8 w2f[2][4];
            #pragma unroll
            for (int nt = 0; nt < 2; ++nt)
                #pragma unroll
                for (int kk = 0; kk < 4; ++kk)
                    w2f[nt][kk] = *(const bf16x8*)&fragbuf[((size_t)(8 + nt * 4 + kk) * 256 + t) * 8];
            const int sb = tt & 1;

            #pragma unroll
            for (int hh = 0; hh < 2; ++hh) {
                // GEMM2 non-swapped (h as A, W2 as B): D2[e][n]
                f32x4 acc2[4][2];
                #pragma unroll
                for (int nt = 0; nt < 2; ++nt) {
                    const float b2 = lb2[wv * 32 + nt * 16 + ln];
                    #pragma unroll
                    for (int et = 0; et < 4; ++et)
                        acc2[et][nt] = (f32x4){b2, b2, b2, b2};
                }
                #pragma unroll
                for (int et = 0; et < 4; ++et) {
                    const int e = hh * 64 + et * 16 + ln;
                    #pragma unroll
                    for (int kk = 0; kk < 4; ++kk) {
                        bf16x8 ah = *(const bf16x8*)&hbuf[e][((kk * 4 + q) ^ lsw) * 8];
                        acc2[et][0] = __builtin_amdgcn_mfma_f32_16x16x32_bf16(ah, w2f[0][kk], acc2[et][0], 0, 0, 0);
                        acc2[et][1] = __builtin_amdgcn_mfma_f32_16x16x32_bf16(ah, w2f[1][kk], acc2[et][1], 0, 0, 0);
                    }
                }
                // run-compress + ds_atomicMax; lane: e = hh*64+et*16+q*4+rr, n = wv*32+nt*16+ln
                #pragma unroll
                for (int et = 0; et < 4; ++et) {
                    const int4 R = *(const int4*)&srow[sb][hh * 64 + et * 16 + q * 4];
                    #pragma unroll
                    for (int nt = 0; nt < 2; ++nt) {
                        unsigned* base = maxbuf + (wv * 32 + nt * 16 + ln);
                        const f32x4 vv = acc2[et][nt];
                        int cur = R.x;
                        float m = vv[0];
                        if (R.y != cur) { atomicMax(base + cur * PITCH, enc_f(m)); cur = R.y; m = vv[1]; }
                        else m = fmaxf(m, vv[1]);
                        if (R.z != cur) { atomicMax(base + cur * PITCH, enc_f(m)); cur = R.z; m = vv[2]; }
                        else m = fmaxf(m, vv[2]);
                        if (R.w != cur) { atomicMax(base + cur * PITCH, enc_f(m)); cur = R.w; m = vv[3]; }
                        else m = fmaxf(m, vv[3]);
                        atomicMax(base + cur * PITCH, enc_f(m));
                    }
                }
                if (hh == 0 && tt + 1 < ntiles) do_pe(tt + 1);  // overlap PE with half1
            }
        }
        __syncthreads();  // einX/einP(tt+1)/srow ready; hbuf free; (last) maxbuf complete
    }

    // ---- epilogue: decode maxbuf -> afin (overlay on hbuf), final GEMM ----
    float* afin = (float*)hbuf;  // 16*128 f32 = 8 KB
    for (int i = t; i < RPB * HD; i += 256) {
        const unsigned e = maxbuf[(i >> 7) * PITCH + (i & 127)];
        afin[i] = (e == ENC_NEG_INF) ? 0.0f : dec_f(e);
    }
    __syncthreads();

    const int j4 = (t & 63) * 4;
    const int rbase = (t >> 6) * 4;
    float facc[4][4];
    const float4 bias = *(const float4*)&gb[j4];
    #pragma unroll
    for (int r = 0; r < 4; ++r) { facc[r][0] = bias.x; facc[r][1] = bias.y; facc[r][2] = bias.z; facc[r][3] = bias.w; }
    for (int k = 0; k < 128; k += 4) {
        float4 w0 = *(const float4*)&gw[(k + 0) * OD + j4];
        float4 w1 = *(const float4*)&gw[(k + 1) * OD + j4];
        float4 w2 = *(const float4*)&gw[(k + 2) * OD + j4];
        float4 w3 = *(const float4*)&gw[(k + 3) * OD + j4];
        #pragma unroll
        for (int r = 0; r < 4; ++r) {
            float4 av = *(const float4*)&afin[(rbase + r) * HD + k];
            facc[r][0] += av.x * w0.x + av.y * w1.x + av.z * w2.x + av.w * w3.x;
            facc[r][1] += av.x * w0.y + av.y * w1.y + av.z * w2.y + av.w * w3.y;
            facc[r][2] += av.x * w0.z + av.y * w1.z + av.z * w2.z + av.w * w3.z;
            facc[r][3] += av.x * w0.w + av.y * w1.w + av.z * w2.w + av.w * w3.w;
        }
    }
    #pragma unroll
    for (int r = 0; r < 4; ++r) {
        float4 v; v.x = facc[r][0]; v.y = facc[r][1]; v.z = facc[r][2]; v.w = facc[r][3];
        *(float4*)&out[(size_t)(m0 + rbase + r) * OD + j4] = v;
    }
}

extern "C" void kernel_launch(void* const* d_in, const int* in_sizes, int n_in,
                              void* d_out, int out_size, void* d_ws, size_t ws_size,
                              hipStream_t stream) {
    const float* x   = (const float*)d_in[0];
    const float* pos = (const float*)d_in[1];
    const int* batch = (const int*)d_in[2];
    const int* idx   = (const int*)d_in[3];
    const int* row   = (const int*)d_in[4];
    const int* col   = (const int*)d_in[5];
    const float* lw1 = (const float*)d_in[6];
    const float* lb1 = (const float*)d_in[7];
    const float* lw2 = (const float*)d_in[8];
    const float* lb2 = (const float*)d_in[9];
    const float* gw  = (const float*)d_in[10];
    const float* gb  = (const float*)d_in[11];
    float* out = (float*)d_out;
    __bf16* fragbuf = (__bf16*)((char*)d_ws + WS_FRAG_OFF);
    int* rowptr     = (int*)((char*)d_ws + WS_ROWPTR_OFF);
    __bf16* xbf     = (__bf16*)((char*)d_ws + WS_XBF_OFF);
    float4* pdbuf   = (float4*)((char*)d_ws + WS_PD_OFF);

    hipLaunchKernelGGL(k_pre, dim3(1 + 65 + 64 + 1024 + 2048), dim3(256), 0, stream,
                       fragbuf, rowptr, xbf, pdbuf, lw1, lw2, x, row, col, pos, batch, idx, out);
    hipLaunchKernelGGL(k_fused, dim3(MM / RPB), dim3(256), 0, stream,
                       xbf, pdbuf, row, col, rowptr, fragbuf, lb1, lb2, gw, gb, out);
}

// Round 16
// 100.356 us; speedup vs baseline: 1.2124x; 1.0130x over previous
//
#include <hip/hip_runtime.h>
#include <math.h>

#define NN 65536
#define MM 16384
#define EE 524288
#define CF 64
#define HD 128
#define OD 256
#define RPB 16        // output rows per block
#define PITCH 129     // maxbuf row pitch (de-banked)

typedef __bf16 bf16x8 __attribute__((ext_vector_type(8)));
typedef __bf16 bf16x4 __attribute__((ext_vector_type(4)));
typedef float f32x4 __attribute__((ext_vector_type(4)));

__device__ __forceinline__ unsigned enc_f(float f) {
    unsigned u = __float_as_uint(f);
    return (u & 0x80000000u) ? ~u : (u | 0x80000000u);
}
__device__ __forceinline__ float dec_f(unsigned e) {
    unsigned u = (e & 0x80000000u) ? (e ^ 0x80000000u) : ~e;
    return __uint_as_float(u);
}
#define ENC_NEG_INF 0x007FFFFFu

__device__ __forceinline__ unsigned bf_bits(float f) {
    __bf16 b = (__bf16)f;
    return (unsigned)__builtin_bit_cast(unsigned short, b);
}

// d_ws layout (>=134 MB proven usable): frag 64K | rowptr 64K | xbf 8M | pd 8M
#define WS_FRAG_OFF 0
#define WS_ROWPTR_OFF 65536
#define WS_XBF_OFF 131072
#define WS_PD_OFF (131072 + 8388608)

// Fused prologue (identical to R11):
// b0: weight frags; b1-65: rowptr; b66-129: side outputs; b130-1153: x->bf16; b1154+: pd.
// fragbuf[fi*256 + t] (bf16x8): fi = (w2?8:0) + nt*4 + kk; element j = W[c][n],
// c = kk*32+q*8+j, n = wv*32+nt*16+ln. Column map (K permuted, weights match):
// [x:0-63][pd:64-66][zero:67][d0 pairs:68-87][d1:88-107][d2:108-127]
__global__ void k_pre(__bf16* __restrict__ fragbuf, int* __restrict__ rowptr,
                      __bf16* __restrict__ xbf, float4* __restrict__ pdbuf,
                      const float* __restrict__ lw1, const float* __restrict__ lw2,
                      const float* __restrict__ x, const int* __restrict__ row,
                      const int* __restrict__ col,
                      const float* __restrict__ pos, const int* __restrict__ batch,
                      const int* __restrict__ idx, float* __restrict__ out) {
    const int b = blockIdx.x;
    const int t = threadIdx.x;
    if (b == 0) {
        const int lane = t & 63;
        const int wv = t >> 6;
        const int q = lane >> 4;
        const int ln = lane & 15;
        #pragma unroll
        for (int fi = 0; fi < 16; ++fi) {
            const int nt = (fi >> 2) & 1, kk = fi & 3;
            const int n = wv * 32 + nt * 16 + ln;
            bf16x8 f;
            #pragma unroll
            for (int j = 0; j < 8; ++j) {
                const int c = kk * 32 + q * 8 + j;
                const int rk = (c < 67) ? c : c - 1;
                f[j] = (fi < 8) ? (__bf16)((c == 67) ? 0.0f : lw1[rk * HD + n])
                                : (__bf16)lw2[c * HD + n];
            }
            *(bf16x8*)&fragbuf[((size_t)fi * 256 + t) * 8] = f;
        }
    } else if (b <= 65) {
        const int i = (b - 1) * 256 + t;
        if (i <= MM) {
            int lo = 0, hi = EE;
            while (lo < hi) { int mid = (lo + hi) >> 1; if (row[mid] < i) lo = mid + 1; else hi = mid; }
            rowptr[i] = lo;
        }
    } else if (b <= 129) {
        const int m = (b - 66) * 256 + t;
        if (m < MM) {
            const int s = idx[m];
            out[MM * OD + m * 3 + 0] = pos[s * 3 + 0];
            out[MM * OD + m * 3 + 1] = pos[s * 3 + 1];
            out[MM * OD + m * 3 + 2] = pos[s * 3 + 2];
            out[MM * OD + MM * 3 + m] = (float)batch[s];
        }
    } else if (b <= 1153) {
        const size_t base = ((size_t)(b - 130) * 256 + t) * 16;
        const float4* xs = (const float4*)(x + base);
        const float4 a = xs[0], c = xs[1], d = xs[2], e = xs[3];
        bf16x8 o0, o1;
        o0[0] = (__bf16)a.x; o0[1] = (__bf16)a.y; o0[2] = (__bf16)a.z; o0[3] = (__bf16)a.w;
        o0[4] = (__bf16)c.x; o0[5] = (__bf16)c.y; o0[6] = (__bf16)c.z; o0[7] = (__bf16)c.w;
        o1[0] = (__bf16)d.x; o1[1] = (__bf16)d.y; o1[2] = (__bf16)d.z; o1[3] = (__bf16)d.w;
        o1[4] = (__bf16)e.x; o1[5] = (__bf16)e.y; o1[6] = (__bf16)e.z; o1[7] = (__bf16)e.w;
        *(bf16x8*)&xbf[base] = o0;
        *(bf16x8*)&xbf[base + 8] = o1;
    } else {
        const int e = (b - 1154) * 256 + t;  // exactly EE threads
        const int r = row[e];
        const int c = col[e];
        const int s = idx[r];
        float4 pd;
        pd.x = pos[c * 3 + 0] - pos[s * 3 + 0];
        pd.y = pos[c * 3 + 1] - pos[s * 3 + 1];
        pd.z = pos[c * 3 + 2] - pos[s * 3 + 2];
        pd.w = 0.0f;
        pdbuf[e] = pd;
    }
}

// Fully fused edge+segmax+out (R11 structure; w1f AND w2f JIT -> low regs, 3 waves/SIMD).
// phase1(tt): w1f JIT; GEMM1(einX, einP) -> hbuf
// phase2(tt): commit(tt+1)->einX + issue(tt+2); w2f JIT; GEMM2 non-swapped;
//             do_pe(tt+1)->einP/srow; run-compress segmax -> ds_atomicMax maxbuf
// epilogue: decode maxbuf -> final 128->256 GEMM -> out
__launch_bounds__(256, 3)
__global__ void k_fused(const __bf16* __restrict__ xbf, const float4* __restrict__ pdbuf,
                        const int* __restrict__ row, const int* __restrict__ col,
                        const int* __restrict__ rowptr, const __bf16* __restrict__ fragbuf,
                        const float* __restrict__ lb1, const float* __restrict__ lb2,
                        const float* __restrict__ gw, const float* __restrict__ gb,
                        float* __restrict__ out) {
    __shared__ __align__(16) __bf16 einX[64][64];          // 8 KB
    __shared__ __align__(16) __bf16 einP[64][64];          // 8 KB
    __shared__ __align__(16) __bf16 hbuf[64][HD];          // 16 KB (reused as afin)
    __shared__ unsigned maxbuf[(RPB + 1) * PITCH];         // 8.6 KB
    __shared__ int srow[2][64];
    const int t = threadIdx.x;
    const int lane = t & 63;
    const int wv = t >> 6;          // 0..3
    const int q = lane >> 4;
    const int ln = lane & 15;
    const int lsw = ln & 7;
    const int m0 = blockIdx.x * RPB;

    const int es = rowptr[m0];
    const int ee = rowptr[m0 + RPB];
    const int ntiles = (ee - es + 63) >> 6;

    for (int i = t; i < (RPB + 1) * PITCH; i += 256) maxbuf[i] = ENC_NEG_INF;

    // register staging from xbf: thread stages edge pe_e, 16-col slice pe_part
    const int pe_e = t >> 2, pe_part = t & 3, pe_esw = pe_e & 7;
    bf16x8 s0, s1;
    auto issue = [&](int tt) {
        const int eg = min(es + tt * 64 + pe_e, EE - 1);
        const int c = col[eg];
        const bf16x8* xr = (const bf16x8*)(xbf + (size_t)c * CF) + pe_part * 2;
        s0 = xr[0]; s1 = xr[1];
    };
    auto commit = [&]() {
        *(bf16x8*)&einX[pe_e][((pe_part * 2 + 0) ^ pe_esw) * 8] = s0;
        *(bf16x8*)&einX[pe_e][((pe_part * 2 + 1) ^ pe_esw) * 8] = s1;
    };
    // PE: pd from pdbuf; one fract+sin+cos + 9 double-angle steps (threads 0-191)
    auto do_pe = [&](int tt) {
        if (t < 192) {
            const int e = t & 63, d = t >> 6;
            const int sb = tt & 1;
            const int eidx = es + tt * 64 + e;
            const int eg = min(eidx, EE - 1);
            const int esw = e & 7;
            const float4 P = pdbuf[eg];
            const float pd = (d == 0) ? P.x : ((d == 1) ? P.y : P.z);
            if (d == 0) {
                srow[sb][e] = (eidx < ee) ? (row[eg] - m0) : RPB;  // dummy row for tails
                uint2 pkt;
                pkt.x = bf_bits(P.x) | (bf_bits(P.y) << 16);
                pkt.y = bf_bits(P.z);  // col 67 = 0
                *(uint2*)&einP[e][esw * 8] = pkt;
            }
            const float fr = __builtin_amdgcn_fractf(pd * 0.5f);
            float sv = __builtin_amdgcn_sinf(fr);
            float cv = __builtin_amdgcn_cosf(fr);
            #pragma unroll
            for (int l = 0; l < 10; ++l) {
                const int jP = 4 + d * 20 + l * 2;  // column-64
                *(unsigned*)&einP[e][((jP >> 3) ^ esw) * 8 + (jP & 7)] =
                    bf_bits(sv) | (bf_bits(cv) << 16);
                const float s2 = 2.0f * sv * cv;
                const float c2 = 1.0f - 2.0f * sv * sv;
                sv = s2; cv = c2;
            }
        }
    };

    float4 b1q[2];
    #pragma unroll
    for (int nt = 0; nt < 2; ++nt)
        b1q[nt] = *(const float4*)&lb1[wv * 32 + nt * 16 + q * 4];

    if (ntiles > 0) {
        issue(0);
        commit();
        do_pe(0);
        if (ntiles > 1) issue(1);  // consumed by commit in phase2(0)
    }
    __syncthreads();  // maxbuf init + einX/einP/srow[0] ready

    for (int tt = 0; tt < ntiles; ++tt) {
        // ---- phase1: w1f JIT (L1/L2-hot), GEMM1 (swapped, W1 as A): D1[n][e] ----
        {
            bf16x8 w1f[2][4];
            #pragma unroll
            for (int nt = 0; nt < 2; ++nt)
                #pragma unroll
                for (int kk = 0; kk < 4; ++kk)
                    w1f[nt][kk] = *(const bf16x8*)&fragbuf[((size_t)(nt * 4 + kk) * 256 + t) * 8];

            f32x4 acc[2][4];
            #pragma unroll
            for (int nt = 0; nt < 2; ++nt)
                #pragma unroll
                for (int et = 0; et < 4; ++et)
                    acc[nt][et] = (f32x4){b1q[nt].x, b1q[nt].y, b1q[nt].z, b1q[nt].w};
            #pragma unroll
            for (int et = 0; et < 4; ++et) {
                const int e = et * 16 + ln;
                bf16x8 a[4];
                a[0] = *(const bf16x8*)&einX[e][(q ^ lsw) * 8];
                a[1] = *(const bf16x8*)&einX[e][((4 + q) ^ lsw) * 8];
                a[2] = *(const bf16x8*)&einP[e][(q ^ lsw) * 8];
                a[3] = *(const bf16x8*)&einP[e][((4 + q) ^ lsw) * 8];
                #pragma unroll
                for (int kk = 0; kk < 4; ++kk) {
                    acc[0][et] = __builtin_amdgcn_mfma_f32_16x16x32_bf16(w1f[0][kk], a[kk], acc[0][et], 0, 0, 0);
                    acc[1][et] = __builtin_amdgcn_mfma_f32_16x16x32_bf16(w1f[1][kk], a[kk], acc[1][et], 0, 0, 0);
                }
            }
            // relu + b64 swizzled stores: lane holds h[e][n = wv*32+nt*16+q*4+r]
            #pragma unroll
            for (int et = 0; et < 4; ++et) {
                const int e = et * 16 + ln;
                #pragma unroll
                for (int nt = 0; nt < 2; ++nt) {
                    bf16x4 hv;
                    hv[0] = (__bf16)fmaxf(acc[nt][et][0], 0.0f);
                    hv[1] = (__bf16)fmaxf(acc[nt][et][1], 0.0f);
                    hv[2] = (__bf16)fmaxf(acc[nt][et][2], 0.0f);
                    hv[3] = (__bf16)fmaxf(acc[nt][et][3], 0.0f);
                    const int chunk = wv * 4 + nt * 2 + (q >> 1);
                    *(bf16x4*)&hbuf[e][((chunk ^ lsw) * 8) + (q & 1) * 4] = hv;
                }
            }
        }
        __syncthreads();  // hbuf ready; einX/einP phase1 reads drained

        // ---- phase2 ----
        {
            if (tt + 1 < ntiles) { commit(); issue(tt + 2 < ntiles ? tt + 2 : tt + 1); }
            bf16x8 w2f[2][4];
            #pragma unroll
            for (int nt = 0; nt < 2; ++nt)
                #pragma unroll
                for (int kk = 0; kk < 4; ++kk)
                    w2f[nt][kk] = *(const bf16x8*)&fragbuf[((size_t)(8 + nt * 4 + kk) * 256 + t) * 8];

            // GEMM2 non-swapped (h as A, W2 as B): D2[e][n]
            f32x4 acc2[4][2];
            #pragma unroll
            for (int nt = 0; nt < 2; ++nt) {
                const float b2 = lb2[wv * 32 + nt * 16 + ln];
                #pragma unroll
                for (int et = 0; et < 4; ++et)
                    acc2[et][nt] = (f32x4){b2, b2, b2, b2};
            }
            #pragma unroll
            for (int et = 0; et < 4; ++et) {
                const int e = et * 16 + ln;
                #pragma unroll
                for (int kk = 0; kk < 4; ++kk) {
                    bf16x8 ah = *(const bf16x8*)&hbuf[e][((kk * 4 + q) ^ lsw) * 8];
                    acc2[et][0] = __builtin_amdgcn_mfma_f32_16x16x32_bf16(ah, w2f[0][kk], acc2[et][0], 0, 0, 0);
                    acc2[et][1] = __builtin_amdgcn_mfma_f32_16x16x32_bf16(ah, w2f[1][kk], acc2[et][1], 0, 0, 0);
                }
            }
            if (tt + 1 < ntiles) do_pe(tt + 1);  // einP phase1 reads drained; srow[sb^1]
            // run-compress + ds_atomicMax; lane: e = et*16+q*4+rr, n = wv*32+nt*16+ln
            const int sb = tt & 1;
            #pragma unroll
            for (int et = 0; et < 4; ++et) {
                const int4 R = *(const int4*)&srow[sb][et * 16 + q * 4];
                #pragma unroll
                for (int nt = 0; nt < 2; ++nt) {
                    unsigned* base = maxbuf + (wv * 32 + nt * 16 + ln);
                    const f32x4 vv = acc2[et][nt];
                    int cur = R.x;
                    float m = vv[0];
                    if (R.y != cur) { atomicMax(base + cur * PITCH, enc_f(m)); cur = R.y; m = vv[1]; }
                    else m = fmaxf(m, vv[1]);
                    if (R.z != cur) { atomicMax(base + cur * PITCH, enc_f(m)); cur = R.z; m = vv[2]; }
                    else m = fmaxf(m, vv[2]);
                    if (R.w != cur) { atomicMax(base + cur * PITCH, enc_f(m)); cur = R.w; m = vv[3]; }
                    else m = fmaxf(m, vv[3]);
                    atomicMax(base + cur * PITCH, enc_f(m));
                }
            }
        }
        __syncthreads();  // einX/einP(tt+1)/srow ready; hbuf free; (last) maxbuf complete
    }

    // ---- epilogue: decode maxbuf -> afin (overlay on hbuf), final GEMM ----
    float* afin = (float*)hbuf;  // 16*128 f32 = 8 KB
    for (int i = t; i < RPB * HD; i += 256) {
        const unsigned e = maxbuf[(i >> 7) * PITCH + (i & 127)];
        afin[i] = (e == ENC_NEG_INF) ? 0.0f : dec_f(e);
    }
    __syncthreads();

    const int j4 = (t & 63) * 4;
    const int rbase = (t >> 6) * 4;
    float facc[4][4];
    const float4 bias = *(const float4*)&gb[j4];
    #pragma unroll
    for (int r = 0; r < 4; ++r) { facc[r][0] = bias.x; facc[r][1] = bias.y; facc[r][2] = bias.z; facc[r][3] = bias.w; }
    for (int k = 0; k < 128; k += 4) {
        float4 w0 = *(const float4*)&gw[(k + 0) * OD + j4];
        float4 w1 = *(const float4*)&gw[(k + 1) * OD + j4];
        float4 w2 = *(const float4*)&gw[(k + 2) * OD + j4];
        float4 w3 = *(const float4*)&gw[(k + 3) * OD + j4];
        #pragma unroll
        for (int r = 0; r < 4; ++r) {
            float4 av = *(const float4*)&afin[(rbase + r) * HD + k];
            facc[r][0] += av.x * w0.x + av.y * w1.x + av.z * w2.x + av.w * w3.x;
            facc[r][1] += av.x * w0.y + av.y * w1.y + av.z * w2.y + av.w * w3.y;
            facc[r][2] += av.x * w0.z + av.y * w1.z + av.z * w2.z + av.w * w3.z;
            facc[r][3] += av.x * w0.w + av.y * w1.w + av.z * w2.w + av.w * w3.w;
        }
    }
    #pragma unroll
    for (int r = 0; r < 4; ++r) {
        float4 v; v.x = facc[r][0]; v.y = facc[r][1]; v.z = facc[r][2]; v.w = facc[r][3];
        *(float4*)&out[(size_t)(m0 + rbase + r) * OD + j4] = v;
    }
}

extern "C" void kernel_launch(void* const* d_in, const int* in_sizes, int n_in,
                              void* d_out, int out_size, void* d_ws, size_t ws_size,
                              hipStream_t stream) {
    const float* x   = (const float*)d_in[0];
    const float* pos = (const float*)d_in[1];
    const int* batch = (const int*)d_in[2];
    const int* idx   = (const int*)d_in[3];
    const int* row   = (const int*)d_in[4];
    const int* col   = (const int*)d_in[5];
    const float* lw1 = (const float*)d_in[6];
    const float* lb1 = (const float*)d_in[7];
    const float* lw2 = (const float*)d_in[8];
    const float* lb2 = (const float*)d_in[9];
    const float* gw  = (const float*)d_in[10];
    const float* gb  = (const float*)d_in[11];
    float* out = (float*)d_out;
    __bf16* fragbuf = (__bf16*)((char*)d_ws + WS_FRAG_OFF);
    int* rowptr     = (int*)((char*)d_ws + WS_ROWPTR_OFF);
    __bf16* xbf     = (__bf16*)((char*)d_ws + WS_XBF_OFF);
    float4* pdbuf   = (float4*)((char*)d_ws + WS_PD_OFF);

    hipLaunchKernelGGL(k_pre, dim3(1 + 65 + 64 + 1024 + 2048), dim3(256), 0, stream,
                       fragbuf, rowptr, xbf, pdbuf, lw1, lw2, x, row, col, pos, batch, idx, out);
    hipLaunchKernelGGL(k_fused, dim3(MM / RPB), dim3(256), 0, stream,
                       xbf, pdbuf, row, col, rowptr, fragbuf, lb1, lb2, gw, gb, out);
}